// Round 5
// baseline (94.400 us; speedup 1.0000x reference)
//
#include <hip/hip_runtime.h>
#include <math.h>
#include <stdint.h>

#define NLEV 8
#define TSIZE 131072
#define TMASK (TSIZE - 1)

__device__ __forceinline__ void transform_pos(
    const float* __restrict__ positions, const float* __restrict__ c2ws,
    const float* __restrict__ aabb, int gid, int S,
    float& posx, float& posy, float& posz, bool& sel)
{
    int r = gid / S;
    const float* p = positions + (size_t)gid * 3;
    const float* c = c2ws + (size_t)r * 12;
    float px = p[0], py = p[1], pz = p[2];
    float c00 = c[0], c01 = c[1], c02 = c[2],  t0 = c[3];
    float c10 = c[4], c11 = c[5], c12 = c[6],  t1 = c[7];
    float c20 = c[8], c21 = c[9], c22 = c[10], t2 = c[11];

    // reference op order, no FMA contraction (selector boundary must match)
    float m0 = __fadd_rn(__fadd_rn(__fmul_rn(c00, px), __fmul_rn(c10, py)), __fmul_rn(c20, pz));
    float m1 = __fadd_rn(__fadd_rn(__fmul_rn(c01, px), __fmul_rn(c11, py)), __fmul_rn(c21, pz));
    float m2 = __fadd_rn(__fadd_rn(__fmul_rn(c02, px), __fmul_rn(c12, py)), __fmul_rn(c22, pz));
    float n0 = __fadd_rn(__fadd_rn(__fmul_rn(c00, t0), __fmul_rn(c10, t1)), __fmul_rn(c20, t2));
    float n1 = __fadd_rn(__fadd_rn(__fmul_rn(c01, t0), __fmul_rn(c11, t1)), __fmul_rn(c21, t2));
    float n2 = __fadd_rn(__fadd_rn(__fmul_rn(c02, t0), __fmul_rn(c12, t1)), __fmul_rn(c22, t2));
    float x0 = __fsub_rn(m0, n0);
    float x1 = __fsub_rn(m1, n1);
    float x2 = __fsub_rn(m2, n2);

    float a0x = aabb[0], a0y = aabb[1], a0z = aabb[2];
    float a1x = aabb[3], a1y = aabb[4], a1z = aabb[5];
    posx = __fdiv_rn(__fsub_rn(x0, a0x), __fsub_rn(a1x, a0x));
    posy = __fdiv_rn(__fsub_rn(x1, a0y), __fsub_rn(a1y, a0y));
    posz = __fdiv_rn(__fsub_rn(x2, a0z), __fsub_rn(a1z, a0z));
    sel = (posx > 0.f) & (posx < 1.f) & (posy > 0.f) & (posy < 1.f) & (posz > 0.f) & (posz < 1.f);
}

// ---------------- K1: per-(sample,level) hash encode ----------------
// block = 256 threads = 32 samples x 8 levels. lane l = tid>>5, s_local = tid&31.
__global__ __launch_bounds__(256) void rif_encode(
    const float* __restrict__ positions,
    const float* __restrict__ c2ws,
    const float* __restrict__ aabb,
    const float* __restrict__ table,
    float* __restrict__ out,
    float* __restrict__ encbuf,   // [16][total]
    int total, int S)
{
    int s_local = threadIdx.x & 31;
    int l = threadIdx.x >> 5;
    int gid = blockIdx.x * 32 + s_local;
    if (gid >= total) return;

    float posx, posy, posz; bool sel;
    transform_pos(positions, c2ws, aabb, gid, S, posx, posy, posz, sel);
    if (!sel) { if (l == 0) out[gid] = 0.f; return; }

    // per-level scale without runtime-indexed array (avoid scratch)
    float sc = (l == 0) ? 16.f : (l == 1) ? 28.f : (l == 2) ? 52.f : (l == 3) ? 95.f
             : (l == 4) ? 172.f : (l == 5) ? 312.f : (l == 6) ? 565.f : 1024.f;

    float sx = posx * sc, sy = posy * sc, sz = posz * sc;
    float fx = floorf(sx), fy = floorf(sy), fz = floorf(sz);
    float wx = sx - fx, wy = sy - fy, wz = sz - fz;
    uint32_t ix = (uint32_t)(int)fx, iy = (uint32_t)(int)fy, iz = (uint32_t)(int)fz;
    uint32_t hy0 = iy * 2654435761u, hy1 = hy0 + 2654435761u;
    uint32_t hz0 = iz * 805459861u,  hz1 = hz0 + 805459861u;
    const float2* tab = (const float2*)table + (size_t)l * TSIZE;

    // issue all 8 gathers (16 VGPRs of payload -> compiler keeps them in flight)
    float2 ft[8];
    #pragma unroll
    for (int cc = 0; cc < 8; ++cc) {
        uint32_t cx = (cc >> 2) & 1, cy = (cc >> 1) & 1, cz = cc & 1;
        uint32_t hh = ((ix + cx) ^ (cy ? hy1 : hy0) ^ (cz ? hz1 : hz0)) & TMASK;
        ft[cc] = tab[hh];
    }
    __builtin_amdgcn_sched_barrier(0);

    float ux = 1.f - wx, uy = 1.f - wy, uz = 1.f - wz;
    float q00 = uy * uz, q01 = uy * wz, q10 = wy * uz, q11 = wy * wz;
    float f0, f1;
    f0 = ft[0].x * (ux * q00); f1 = ft[0].y * (ux * q00);
    f0 = fmaf(ft[1].x, ux * q01, f0); f1 = fmaf(ft[1].y, ux * q01, f1);
    f0 = fmaf(ft[2].x, ux * q10, f0); f1 = fmaf(ft[2].y, ux * q10, f1);
    f0 = fmaf(ft[3].x, ux * q11, f0); f1 = fmaf(ft[3].y, ux * q11, f1);
    f0 = fmaf(ft[4].x, wx * q00, f0); f1 = fmaf(ft[4].y, wx * q00, f1);
    f0 = fmaf(ft[5].x, wx * q01, f0); f1 = fmaf(ft[5].y, wx * q01, f1);
    f0 = fmaf(ft[6].x, wx * q10, f0); f1 = fmaf(ft[6].y, wx * q10, f1);
    f0 = fmaf(ft[7].x, wx * q11, f0); f1 = fmaf(ft[7].y, wx * q11, f1);

    // transposed planes: [j][gid] -> coalesced across s_local lanes
    encbuf[(size_t)(2 * l) * total + gid] = f0;
    encbuf[(size_t)(2 * l + 1) * total + gid] = f1;
}

// ---------------- K2: compacted MLP ----------------
__global__ __launch_bounds__(256, 2) void rif_mlp(
    const float* __restrict__ positions,
    const float* __restrict__ c2ws,
    const float* __restrict__ aabb,
    const float* __restrict__ w1, const float* __restrict__ b1,
    const float* __restrict__ w2, const float* __restrict__ b2,
    const float* __restrict__ hw1, const float* __restrict__ hb1,
    const float* __restrict__ hw2, const float* __restrict__ hb2,
    float* __restrict__ out,
    const float* __restrict__ encbuf,
    int total, int S)
{
    __shared__ int sIdx[256];
    __shared__ int wbase[4];
    __shared__ int sCnt;

    int gid = blockIdx.x * 256 + threadIdx.x;
    bool sel = false;
    if (gid < total) {
        float posx, posy, posz;
        transform_pos(positions, c2ws, aabb, gid, S, posx, posy, posz, sel);
    }

    unsigned long long m = __ballot(sel);
    int lane = threadIdx.x & 63;
    int wid  = threadIdx.x >> 6;
    int pre  = __popcll(m & ((1ull << lane) - 1ull));
    if (lane == 0) wbase[wid] = __popcll(m);
    __syncthreads();
    if (threadIdx.x == 0) {
        int s = 0;
        #pragma unroll
        for (int w = 0; w < 4; ++w) { int t = wbase[w]; wbase[w] = s; s += t; }
        sCnt = s;
    }
    __syncthreads();
    if (sel) sIdx[wbase[wid] + pre] = threadIdx.x;
    __syncthreads();

    int cnt = sCnt;
    int t = threadIdx.x;
    if (t >= cnt) return;
    int ogid = blockIdx.x * 256 + sIdx[t];

    float enc[16];
    #pragma unroll
    for (int j = 0; j < 16; ++j) enc[j] = encbuf[(size_t)j * total + ogid];

    float h1[32];
    #pragma unroll
    for (int j = 0; j < 32; ++j) h1[j] = b1[j];
    #pragma unroll
    for (int i = 0; i < 16; ++i) {
        float e = enc[i];
        #pragma unroll
        for (int j = 0; j < 32; ++j) h1[j] = fmaf(e, w1[i * 32 + j], h1[j]);
    }
    #pragma unroll
    for (int j = 0; j < 32; ++j) h1[j] = fmaxf(h1[j], 0.f);

    float h2[16];
    #pragma unroll
    for (int j = 0; j < 16; ++j) h2[j] = b2[j];
    #pragma unroll
    for (int i = 0; i < 32; ++i) {
        float e = h1[i];
        #pragma unroll
        for (int j = 0; j < 16; ++j) h2[j] = fmaf(e, w2[i * 16 + j], h2[j]);
    }

    float o = hb2[0];
    #pragma unroll
    for (int j = 0; j < 64; ++j) {
        float acc = hb1[j];
        #pragma unroll
        for (int i = 0; i < 16; ++i) acc = fmaf(h2[i], hw1[i * 64 + j], acc);
        o = fmaf(fmaxf(acc, 0.f), hw2[j], o);
    }

    float x = o - 5.0f;
    out[ogid] = 1.0f / (1.0f + expf(-x));
}

// ---------------- Fallback: R4 fused kernel (if ws too small) ----------------
__global__ __launch_bounds__(256, 2) void rif_fused(
    const float* __restrict__ positions,
    const float* __restrict__ c2ws,
    const float* __restrict__ aabb,
    const float* __restrict__ table,
    const float* __restrict__ w1, const float* __restrict__ b1,
    const float* __restrict__ w2, const float* __restrict__ b2,
    const float* __restrict__ hw1, const float* __restrict__ hb1,
    const float* __restrict__ hw2, const float* __restrict__ hb2,
    float* __restrict__ out, int total, int S)
{
    int gid = blockIdx.x * 256 + threadIdx.x;
    if (gid >= total) return;
    float posx, posy, posz; bool sel;
    transform_pos(positions, c2ws, aabb, gid, S, posx, posy, posz, sel);
    if (!sel) { out[gid] = 0.f; return; }

    const float kScale[8] = {16.f, 28.f, 52.f, 95.f, 172.f, 312.f, 565.f, 1024.f};
    float enc[16];
    #pragma unroll
    for (int l = 0; l < NLEV; ++l) {
        float sc = kScale[l];
        float sx = posx * sc, sy = posy * sc, sz = posz * sc;
        float fx = floorf(sx), fy = floorf(sy), fz = floorf(sz);
        float wx = sx - fx, wy = sy - fy, wz = sz - fz;
        uint32_t ix = (uint32_t)(int)fx, iy = (uint32_t)(int)fy, iz = (uint32_t)(int)fz;
        uint32_t hy0 = iy * 2654435761u, hy1 = hy0 + 2654435761u;
        uint32_t hz0 = iz * 805459861u,  hz1 = hz0 + 805459861u;
        const float2* tab = (const float2*)table + (size_t)l * TSIZE;
        float f0 = 0.f, f1 = 0.f;
        #pragma unroll
        for (int cc = 0; cc < 8; ++cc) {
            uint32_t cx = (cc >> 2) & 1, cy = (cc >> 1) & 1, cz = cc & 1;
            uint32_t hh = ((ix + cx) ^ (cy ? hy1 : hy0) ^ (cz ? hz1 : hz0)) & TMASK;
            float wgt = (cx ? wx : 1.f - wx) * (cy ? wy : 1.f - wy) * (cz ? wz : 1.f - wz);
            float2 ftv = tab[hh];
            f0 = fmaf(ftv.x, wgt, f0);
            f1 = fmaf(ftv.y, wgt, f1);
        }
        enc[2 * l] = f0;
        enc[2 * l + 1] = f1;
    }

    float h1[32];
    #pragma unroll
    for (int j = 0; j < 32; ++j) h1[j] = b1[j];
    #pragma unroll
    for (int i = 0; i < 16; ++i) {
        float e = enc[i];
        #pragma unroll
        for (int j = 0; j < 32; ++j) h1[j] = fmaf(e, w1[i * 32 + j], h1[j]);
    }
    #pragma unroll
    for (int j = 0; j < 32; ++j) h1[j] = fmaxf(h1[j], 0.f);

    float h2[16];
    #pragma unroll
    for (int j = 0; j < 16; ++j) h2[j] = b2[j];
    #pragma unroll
    for (int i = 0; i < 32; ++i) {
        float e = h1[i];
        #pragma unroll
        for (int j = 0; j < 16; ++j) h2[j] = fmaf(e, w2[i * 16 + j], h2[j]);
    }

    float o = hb2[0];
    #pragma unroll
    for (int j = 0; j < 64; ++j) {
        float acc = hb1[j];
        #pragma unroll
        for (int i = 0; i < 16; ++i) acc = fmaf(h2[i], hw1[i * 64 + j], acc);
        o = fmaf(fmaxf(acc, 0.f), hw2[j], o);
    }

    float x = o - 5.0f;
    out[gid] = 1.0f / (1.0f + expf(-x));
}

extern "C" void kernel_launch(void* const* d_in, const int* in_sizes, int n_in,
                              void* d_out, int out_size, void* d_ws, size_t ws_size,
                              hipStream_t stream) {
    const float* positions = (const float*)d_in[0];
    const float* c2ws      = (const float*)d_in[1];
    const float* aabb      = (const float*)d_in[2];
    const float* table     = (const float*)d_in[3];
    const float* w1  = (const float*)d_in[4];
    const float* b1  = (const float*)d_in[5];
    const float* w2  = (const float*)d_in[6];
    const float* b2  = (const float*)d_in[7];
    const float* hw1 = (const float*)d_in[8];
    const float* hb1 = (const float*)d_in[9];
    const float* hw2 = (const float*)d_in[10];
    const float* hb2 = (const float*)d_in[11];

    int R = in_sizes[1] / 12;
    int total = in_sizes[0] / 3;
    int S = total / R;

    size_t needed = (size_t)16 * (size_t)total * sizeof(float);
    if (ws_size >= needed) {
        float* encbuf = (float*)d_ws;
        int blocks1 = (total + 31) / 32;   // 32 samples x 8 levels per block
        hipLaunchKernelGGL(rif_encode, dim3(blocks1), dim3(256), 0, stream,
                           positions, c2ws, aabb, table,
                           (float*)d_out, encbuf, total, S);
        int blocks2 = (total + 255) / 256;
        hipLaunchKernelGGL(rif_mlp, dim3(blocks2), dim3(256), 0, stream,
                           positions, c2ws, aabb,
                           w1, b1, w2, b2, hw1, hb1, hw2, hb2,
                           (float*)d_out, encbuf, total, S);
    } else {
        int blocks = (total + 255) / 256;
        hipLaunchKernelGGL(rif_fused, dim3(blocks), dim3(256), 0, stream,
                           positions, c2ws, aabb, table,
                           w1, b1, w2, b2, hw1, hb1, hw2, hb2,
                           (float*)d_out, total, S);
    }
}

// Round 6
// 82.440 us; speedup vs baseline: 1.1451x; 1.1451x over previous
//
#include <hip/hip_runtime.h>
#include <math.h>
#include <stdint.h>

#define NLEV 8
#define TSIZE 131072
#define TMASK (TSIZE - 1)

__device__ __forceinline__ void transform_pos(
    const float* __restrict__ positions, const float* __restrict__ c2ws,
    const float* __restrict__ aabb, int gid, int S,
    float& posx, float& posy, float& posz, bool& sel)
{
    int r = gid / S;
    const float* p = positions + (size_t)gid * 3;
    const float* c = c2ws + (size_t)r * 12;
    float px = __builtin_nontemporal_load(p + 0);
    float py = __builtin_nontemporal_load(p + 1);
    float pz = __builtin_nontemporal_load(p + 2);
    float c00 = c[0], c01 = c[1], c02 = c[2],  t0 = c[3];
    float c10 = c[4], c11 = c[5], c12 = c[6],  t1 = c[7];
    float c20 = c[8], c21 = c[9], c22 = c[10], t2 = c[11];

    // reference op order, no FMA contraction (selector boundary must match)
    float m0 = __fadd_rn(__fadd_rn(__fmul_rn(c00, px), __fmul_rn(c10, py)), __fmul_rn(c20, pz));
    float m1 = __fadd_rn(__fadd_rn(__fmul_rn(c01, px), __fmul_rn(c11, py)), __fmul_rn(c21, pz));
    float m2 = __fadd_rn(__fadd_rn(__fmul_rn(c02, px), __fmul_rn(c12, py)), __fmul_rn(c22, pz));
    float n0 = __fadd_rn(__fadd_rn(__fmul_rn(c00, t0), __fmul_rn(c10, t1)), __fmul_rn(c20, t2));
    float n1 = __fadd_rn(__fadd_rn(__fmul_rn(c01, t0), __fmul_rn(c11, t1)), __fmul_rn(c21, t2));
    float n2 = __fadd_rn(__fadd_rn(__fmul_rn(c02, t0), __fmul_rn(c12, t1)), __fmul_rn(c22, t2));
    float x0 = __fsub_rn(m0, n0);
    float x1 = __fsub_rn(m1, n1);
    float x2 = __fsub_rn(m2, n2);

    float a0x = aabb[0], a0y = aabb[1], a0z = aabb[2];
    float a1x = aabb[3], a1y = aabb[4], a1z = aabb[5];
    posx = __fdiv_rn(__fsub_rn(x0, a0x), __fsub_rn(a1x, a0x));
    posy = __fdiv_rn(__fsub_rn(x1, a0y), __fsub_rn(a1y, a0y));
    posz = __fdiv_rn(__fsub_rn(x2, a0z), __fsub_rn(a1z, a0z));
    sel = (posx > 0.f) & (posx < 1.f) & (posy > 0.f) & (posy < 1.f) & (posz > 0.f) & (posz < 1.f);
}

// ---------------- K1: level-major hash encode ----------------
// block = 256 threads = 128 samples x 2 paired levels (g, 7-g), g = blockIdx%4.
// XCD k (blocks round-robin %8) sees only pair-group k%4 -> 2 MB table working set per XCD L2.
__global__ __launch_bounds__(256) void rif_encode_lm(
    const float* __restrict__ positions,
    const float* __restrict__ c2ws,
    const float* __restrict__ aabb,
    const float* __restrict__ table,
    float* __restrict__ out,
    float* __restrict__ encbuf,   // [16][total]
    int total, int S)
{
    int g     = blockIdx.x & 3;
    int chunk = blockIdx.x >> 2;
    int half  = threadIdx.x >> 7;        // 0: level g (waves 0-1), 1: level 7-g (waves 2-3)
    int sl    = threadIdx.x & 127;
    int gid   = chunk * 128 + sl;
    if (gid >= total) return;
    int l = half ? (7 - g) : g;

    float posx, posy, posz; bool sel;
    transform_pos(positions, c2ws, aabb, gid, S, posx, posy, posz, sel);
    if (!sel) {
        if (g == 0 && half == 0) __builtin_nontemporal_store(0.f, out + gid);
        return;
    }

    float sc = (l == 0) ? 16.f : (l == 1) ? 28.f : (l == 2) ? 52.f : (l == 3) ? 95.f
             : (l == 4) ? 172.f : (l == 5) ? 312.f : (l == 6) ? 565.f : 1024.f;

    float sx = posx * sc, sy = posy * sc, sz = posz * sc;
    float fx = floorf(sx), fy = floorf(sy), fz = floorf(sz);
    float wx = sx - fx, wy = sy - fy, wz = sz - fz;
    uint32_t ix = (uint32_t)(int)fx, iy = (uint32_t)(int)fy, iz = (uint32_t)(int)fz;
    uint32_t hy0 = iy * 2654435761u, hy1 = hy0 + 2654435761u;
    uint32_t hz0 = iz * 805459861u,  hz1 = hz0 + 805459861u;
    const float2* tab = (const float2*)table + (size_t)l * TSIZE;

    float2 ft[8];
    #pragma unroll
    for (int cc = 0; cc < 8; ++cc) {
        uint32_t cx = (cc >> 2) & 1, cy = (cc >> 1) & 1, cz = cc & 1;
        uint32_t hh = ((ix + cx) ^ (cy ? hy1 : hy0) ^ (cz ? hz1 : hz0)) & TMASK;
        ft[cc] = tab[hh];
    }
    __builtin_amdgcn_sched_barrier(0);

    float ux = 1.f - wx, uy = 1.f - wy, uz = 1.f - wz;
    float q00 = uy * uz, q01 = uy * wz, q10 = wy * uz, q11 = wy * wz;
    float f0, f1;
    f0 = ft[0].x * (ux * q00); f1 = ft[0].y * (ux * q00);
    f0 = fmaf(ft[1].x, ux * q01, f0); f1 = fmaf(ft[1].y, ux * q01, f1);
    f0 = fmaf(ft[2].x, ux * q10, f0); f1 = fmaf(ft[2].y, ux * q10, f1);
    f0 = fmaf(ft[3].x, ux * q11, f0); f1 = fmaf(ft[3].y, ux * q11, f1);
    f0 = fmaf(ft[4].x, wx * q00, f0); f1 = fmaf(ft[4].y, wx * q00, f1);
    f0 = fmaf(ft[5].x, wx * q01, f0); f1 = fmaf(ft[5].y, wx * q01, f1);
    f0 = fmaf(ft[6].x, wx * q10, f0); f1 = fmaf(ft[6].y, wx * q10, f1);
    f0 = fmaf(ft[7].x, wx * q11, f0); f1 = fmaf(ft[7].y, wx * q11, f1);

    __builtin_nontemporal_store(f0, encbuf + (size_t)(2 * l) * total + gid);
    __builtin_nontemporal_store(f1, encbuf + (size_t)(2 * l + 1) * total + gid);
}

// ---------------- K2: compacted MLP ----------------
__global__ __launch_bounds__(256, 2) void rif_mlp(
    const float* __restrict__ positions,
    const float* __restrict__ c2ws,
    const float* __restrict__ aabb,
    const float* __restrict__ w1, const float* __restrict__ b1,
    const float* __restrict__ w2, const float* __restrict__ b2,
    const float* __restrict__ hw1, const float* __restrict__ hb1,
    const float* __restrict__ hw2, const float* __restrict__ hb2,
    float* __restrict__ out,
    const float* __restrict__ encbuf,
    int total, int S)
{
    __shared__ int sIdx[256];
    __shared__ int wbase[4];
    __shared__ int sCnt;

    int gid = blockIdx.x * 256 + threadIdx.x;
    bool sel = false;
    if (gid < total) {
        float posx, posy, posz;
        transform_pos(positions, c2ws, aabb, gid, S, posx, posy, posz, sel);
    }

    unsigned long long m = __ballot(sel);
    int lane = threadIdx.x & 63;
    int wid  = threadIdx.x >> 6;
    int pre  = __popcll(m & ((1ull << lane) - 1ull));
    if (lane == 0) wbase[wid] = __popcll(m);
    __syncthreads();
    if (threadIdx.x == 0) {
        int s = 0;
        #pragma unroll
        for (int w = 0; w < 4; ++w) { int t = wbase[w]; wbase[w] = s; s += t; }
        sCnt = s;
    }
    __syncthreads();
    if (sel) sIdx[wbase[wid] + pre] = threadIdx.x;
    __syncthreads();

    int cnt = sCnt;
    int t = threadIdx.x;
    if (t >= cnt) return;
    int ogid = blockIdx.x * 256 + sIdx[t];

    float enc[16];
    #pragma unroll
    for (int j = 0; j < 16; ++j) enc[j] = encbuf[(size_t)j * total + ogid];

    float h1[32];
    #pragma unroll
    for (int j = 0; j < 32; ++j) h1[j] = b1[j];
    #pragma unroll
    for (int i = 0; i < 16; ++i) {
        float e = enc[i];
        #pragma unroll
        for (int j = 0; j < 32; ++j) h1[j] = fmaf(e, w1[i * 32 + j], h1[j]);
    }
    #pragma unroll
    for (int j = 0; j < 32; ++j) h1[j] = fmaxf(h1[j], 0.f);

    float h2[16];
    #pragma unroll
    for (int j = 0; j < 16; ++j) h2[j] = b2[j];
    #pragma unroll
    for (int i = 0; i < 32; ++i) {
        float e = h1[i];
        #pragma unroll
        for (int j = 0; j < 16; ++j) h2[j] = fmaf(e, w2[i * 16 + j], h2[j]);
    }

    float o = hb2[0];
    #pragma unroll
    for (int j = 0; j < 64; ++j) {
        float acc = hb1[j];
        #pragma unroll
        for (int i = 0; i < 16; ++i) acc = fmaf(h2[i], hw1[i * 64 + j], acc);
        o = fmaf(fmaxf(acc, 0.f), hw2[j], o);
    }

    float x = o - 5.0f;
    out[ogid] = 1.0f / (1.0f + expf(-x));
}

// ---------------- Fallback: fused kernel (if ws too small) ----------------
__global__ __launch_bounds__(256, 2) void rif_fused(
    const float* __restrict__ positions,
    const float* __restrict__ c2ws,
    const float* __restrict__ aabb,
    const float* __restrict__ table,
    const float* __restrict__ w1, const float* __restrict__ b1,
    const float* __restrict__ w2, const float* __restrict__ b2,
    const float* __restrict__ hw1, const float* __restrict__ hb1,
    const float* __restrict__ hw2, const float* __restrict__ hb2,
    float* __restrict__ out, int total, int S)
{
    int gid = blockIdx.x * 256 + threadIdx.x;
    if (gid >= total) return;
    float posx, posy, posz; bool sel;
    transform_pos(positions, c2ws, aabb, gid, S, posx, posy, posz, sel);
    if (!sel) { out[gid] = 0.f; return; }

    const float kScale[8] = {16.f, 28.f, 52.f, 95.f, 172.f, 312.f, 565.f, 1024.f};
    float enc[16];
    #pragma unroll
    for (int l = 0; l < NLEV; ++l) {
        float sc = kScale[l];
        float sx = posx * sc, sy = posy * sc, sz = posz * sc;
        float fx = floorf(sx), fy = floorf(sy), fz = floorf(sz);
        float wx = sx - fx, wy = sy - fy, wz = sz - fz;
        uint32_t ix = (uint32_t)(int)fx, iy = (uint32_t)(int)fy, iz = (uint32_t)(int)fz;
        uint32_t hy0 = iy * 2654435761u, hy1 = hy0 + 2654435761u;
        uint32_t hz0 = iz * 805459861u,  hz1 = hz0 + 805459861u;
        const float2* tab = (const float2*)table + (size_t)l * TSIZE;
        float f0 = 0.f, f1 = 0.f;
        #pragma unroll
        for (int cc = 0; cc < 8; ++cc) {
            uint32_t cx = (cc >> 2) & 1, cy = (cc >> 1) & 1, cz = cc & 1;
            uint32_t hh = ((ix + cx) ^ (cy ? hy1 : hy0) ^ (cz ? hz1 : hz0)) & TMASK;
            float wgt = (cx ? wx : 1.f - wx) * (cy ? wy : 1.f - wy) * (cz ? wz : 1.f - wz);
            float2 ftv = tab[hh];
            f0 = fmaf(ftv.x, wgt, f0);
            f1 = fmaf(ftv.y, wgt, f1);
        }
        enc[2 * l] = f0;
        enc[2 * l + 1] = f1;
    }

    float h1[32];
    #pragma unroll
    for (int j = 0; j < 32; ++j) h1[j] = b1[j];
    #pragma unroll
    for (int i = 0; i < 16; ++i) {
        float e = enc[i];
        #pragma unroll
        for (int j = 0; j < 32; ++j) h1[j] = fmaf(e, w1[i * 32 + j], h1[j]);
    }
    #pragma unroll
    for (int j = 0; j < 32; ++j) h1[j] = fmaxf(h1[j], 0.f);

    float h2[16];
    #pragma unroll
    for (int j = 0; j < 16; ++j) h2[j] = b2[j];
    #pragma unroll
    for (int i = 0; i < 32; ++i) {
        float e = h1[i];
        #pragma unroll
        for (int j = 0; j < 16; ++j) h2[j] = fmaf(e, w2[i * 16 + j], h2[j]);
    }

    float o = hb2[0];
    #pragma unroll
    for (int j = 0; j < 64; ++j) {
        float acc = hb1[j];
        #pragma unroll
        for (int i = 0; i < 16; ++i) acc = fmaf(h2[i], hw1[i * 64 + j], acc);
        o = fmaf(fmaxf(acc, 0.f), hw2[j], o);
    }

    float x = o - 5.0f;
    out[gid] = 1.0f / (1.0f + expf(-x));
}

extern "C" void kernel_launch(void* const* d_in, const int* in_sizes, int n_in,
                              void* d_out, int out_size, void* d_ws, size_t ws_size,
                              hipStream_t stream) {
    const float* positions = (const float*)d_in[0];
    const float* c2ws      = (const float*)d_in[1];
    const float* aabb      = (const float*)d_in[2];
    const float* table     = (const float*)d_in[3];
    const float* w1  = (const float*)d_in[4];
    const float* b1  = (const float*)d_in[5];
    const float* w2  = (const float*)d_in[6];
    const float* b2  = (const float*)d_in[7];
    const float* hw1 = (const float*)d_in[8];
    const float* hb1 = (const float*)d_in[9];
    const float* hw2 = (const float*)d_in[10];
    const float* hb2 = (const float*)d_in[11];

    int R = in_sizes[1] / 12;
    int total = in_sizes[0] / 3;
    int S = total / R;

    size_t needed = (size_t)16 * (size_t)total * sizeof(float);
    if (ws_size >= needed) {
        float* encbuf = (float*)d_ws;
        int nchunks = (total + 127) / 128;    // 128 samples x 2 levels per block
        hipLaunchKernelGGL(rif_encode_lm, dim3(nchunks * 4), dim3(256), 0, stream,
                           positions, c2ws, aabb, table,
                           (float*)d_out, encbuf, total, S);
        int blocks2 = (total + 255) / 256;
        hipLaunchKernelGGL(rif_mlp, dim3(blocks2), dim3(256), 0, stream,
                           positions, c2ws, aabb,
                           w1, b1, w2, b2, hw1, hb1, hw2, hb2,
                           (float*)d_out, encbuf, total, S);
    } else {
        int blocks = (total + 255) / 256;
        hipLaunchKernelGGL(rif_fused, dim3(blocks), dim3(256), 0, stream,
                           positions, c2ws, aabb, table,
                           w1, b1, w2, b2, hw1, hb1, hw2, hb2,
                           (float*)d_out, total, S);
    }
}

// Round 7
// 78.349 us; speedup vs baseline: 1.2049x; 1.0522x over previous
//
#include <hip/hip_runtime.h>
#include <math.h>
#include <stdint.h>

#define NLEV 8
#define TSIZE 131072
#define TMASK (TSIZE - 1)

// ---------------- K0: transform once per sample ----------------
__global__ __launch_bounds__(256) void rif_xform(
    const float* __restrict__ positions,
    const float* __restrict__ c2ws,
    const float* __restrict__ aabb,
    float* __restrict__ out,
    float4* __restrict__ pos4,
    int total, int S)
{
    int gid = blockIdx.x * 256 + threadIdx.x;
    if (gid >= total) return;
    int r = gid / S;
    const float* p = positions + (size_t)gid * 3;
    const float* c = c2ws + (size_t)r * 12;
    float px = p[0], py = p[1], pz = p[2];
    float c00 = c[0], c01 = c[1], c02 = c[2],  t0 = c[3];
    float c10 = c[4], c11 = c[5], c12 = c[6],  t1 = c[7];
    float c20 = c[8], c21 = c[9], c22 = c[10], t2 = c[11];

    // reference op order, no FMA contraction (selector boundary must match)
    float m0 = __fadd_rn(__fadd_rn(__fmul_rn(c00, px), __fmul_rn(c10, py)), __fmul_rn(c20, pz));
    float m1 = __fadd_rn(__fadd_rn(__fmul_rn(c01, px), __fmul_rn(c11, py)), __fmul_rn(c21, pz));
    float m2 = __fadd_rn(__fadd_rn(__fmul_rn(c02, px), __fmul_rn(c12, py)), __fmul_rn(c22, pz));
    float n0 = __fadd_rn(__fadd_rn(__fmul_rn(c00, t0), __fmul_rn(c10, t1)), __fmul_rn(c20, t2));
    float n1 = __fadd_rn(__fadd_rn(__fmul_rn(c01, t0), __fmul_rn(c11, t1)), __fmul_rn(c21, t2));
    float n2 = __fadd_rn(__fadd_rn(__fmul_rn(c02, t0), __fmul_rn(c12, t1)), __fmul_rn(c22, t2));
    float x0 = __fsub_rn(m0, n0);
    float x1 = __fsub_rn(m1, n1);
    float x2 = __fsub_rn(m2, n2);

    float a0x = aabb[0], a0y = aabb[1], a0z = aabb[2];
    float a1x = aabb[3], a1y = aabb[4], a1z = aabb[5];
    float posx = __fdiv_rn(__fsub_rn(x0, a0x), __fsub_rn(a1x, a0x));
    float posy = __fdiv_rn(__fsub_rn(x1, a0y), __fsub_rn(a1y, a0y));
    float posz = __fdiv_rn(__fsub_rn(x2, a0z), __fsub_rn(a1z, a0z));
    bool sel = (posx > 0.f) & (posx < 1.f) & (posy > 0.f) & (posy < 1.f) & (posz > 0.f) & (posz < 1.f);

    if (!sel) out[gid] = 0.f;
    pos4[gid] = make_float4(posx, posy, posz, sel ? 1.f : 0.f);
}

// ---------------- K1: level-major hash encode ----------------
// block = 256 threads = 128 samples x 2 paired levels (g, 7-g), g = blockIdx%4.
// Blocks round-robin XCDs -> each XCD touches only 2 subtables (2 MB) -> L2-resident.
__global__ __launch_bounds__(256) void rif_enc(
    const float4* __restrict__ pos4,
    const float* __restrict__ table,
    float* __restrict__ encbuf,   // AoS: [total][16]
    int total)
{
    int g     = blockIdx.x & 3;
    int chunk = blockIdx.x >> 2;
    int half  = threadIdx.x >> 7;        // 0: level g, 1: level 7-g
    int sl    = threadIdx.x & 127;
    int gid   = chunk * 128 + sl;
    if (gid >= total) return;
    int l = half ? (7 - g) : g;

    float4 pp = pos4[gid];
    if (pp.w == 0.f) return;

    float sc = (l == 0) ? 16.f : (l == 1) ? 28.f : (l == 2) ? 52.f : (l == 3) ? 95.f
             : (l == 4) ? 172.f : (l == 5) ? 312.f : (l == 6) ? 565.f : 1024.f;

    float sx = pp.x * sc, sy = pp.y * sc, sz = pp.z * sc;
    float fx = floorf(sx), fy = floorf(sy), fz = floorf(sz);
    float wx = sx - fx, wy = sy - fy, wz = sz - fz;
    uint32_t ix = (uint32_t)(int)fx, iy = (uint32_t)(int)fy, iz = (uint32_t)(int)fz;
    uint32_t hy0 = iy * 2654435761u, hy1 = hy0 + 2654435761u;
    uint32_t hz0 = iz * 805459861u,  hz1 = hz0 + 805459861u;
    const float2* tab = (const float2*)table + (size_t)l * TSIZE;

    float2 ft[8];
    #pragma unroll
    for (int cc = 0; cc < 8; ++cc) {
        uint32_t cx = (cc >> 2) & 1, cy = (cc >> 1) & 1, cz = cc & 1;
        uint32_t hh = ((ix + cx) ^ (cy ? hy1 : hy0) ^ (cz ? hz1 : hz0)) & TMASK;
        ft[cc] = tab[hh];
    }
    __builtin_amdgcn_sched_barrier(0);

    float ux = 1.f - wx, uy = 1.f - wy, uz = 1.f - wz;
    float q00 = uy * uz, q01 = uy * wz, q10 = wy * uz, q11 = wy * wz;
    float f0, f1;
    f0 = ft[0].x * (ux * q00); f1 = ft[0].y * (ux * q00);
    f0 = fmaf(ft[1].x, ux * q01, f0); f1 = fmaf(ft[1].y, ux * q01, f1);
    f0 = fmaf(ft[2].x, ux * q10, f0); f1 = fmaf(ft[2].y, ux * q10, f1);
    f0 = fmaf(ft[3].x, ux * q11, f0); f1 = fmaf(ft[3].y, ux * q11, f1);
    f0 = fmaf(ft[4].x, wx * q00, f0); f1 = fmaf(ft[4].y, wx * q00, f1);
    f0 = fmaf(ft[5].x, wx * q01, f0); f1 = fmaf(ft[5].y, wx * q01, f1);
    f0 = fmaf(ft[6].x, wx * q10, f0); f1 = fmaf(ft[6].y, wx * q10, f1);
    f0 = fmaf(ft[7].x, wx * q11, f0); f1 = fmaf(ft[7].y, wx * q11, f1);

    // AoS: sample line [gid][16]; this thread owns bytes [2l..2l+1]
    *(float2*)(encbuf + (size_t)gid * 16 + 2 * l) = make_float2(f0, f1);
}

// ---------------- K2: MLP (no compaction; coalesced AoS enc reads) ----------------
__global__ __launch_bounds__(256, 2) void rif_mlp(
    const float4* __restrict__ pos4,
    const float* __restrict__ w1, const float* __restrict__ b1,
    const float* __restrict__ w2, const float* __restrict__ b2,
    const float* __restrict__ hw1, const float* __restrict__ hb1,
    const float* __restrict__ hw2, const float* __restrict__ hb2,
    float* __restrict__ out,
    const float* __restrict__ encbuf,
    int total)
{
    int gid = blockIdx.x * 256 + threadIdx.x;
    if (gid >= total) return;
    if (pos4[gid].w == 0.f) return;   // out already zeroed by K0

    float enc[16];
    const float4* e4 = (const float4*)(encbuf + (size_t)gid * 16);
    #pragma unroll
    for (int q = 0; q < 4; ++q) {
        float4 v = e4[q];
        enc[4 * q + 0] = v.x; enc[4 * q + 1] = v.y;
        enc[4 * q + 2] = v.z; enc[4 * q + 3] = v.w;
    }

    float h1[32];
    #pragma unroll
    for (int j = 0; j < 32; ++j) h1[j] = b1[j];
    #pragma unroll
    for (int i = 0; i < 16; ++i) {
        float e = enc[i];
        #pragma unroll
        for (int j = 0; j < 32; ++j) h1[j] = fmaf(e, w1[i * 32 + j], h1[j]);
    }
    #pragma unroll
    for (int j = 0; j < 32; ++j) h1[j] = fmaxf(h1[j], 0.f);

    float h2[16];
    #pragma unroll
    for (int j = 0; j < 16; ++j) h2[j] = b2[j];
    #pragma unroll
    for (int i = 0; i < 32; ++i) {
        float e = h1[i];
        #pragma unroll
        for (int j = 0; j < 16; ++j) h2[j] = fmaf(e, w2[i * 16 + j], h2[j]);
    }

    float o = hb2[0];
    #pragma unroll
    for (int j = 0; j < 64; ++j) {
        float acc = hb1[j];
        #pragma unroll
        for (int i = 0; i < 16; ++i) acc = fmaf(h2[i], hw1[i * 64 + j], acc);
        o = fmaf(fmaxf(acc, 0.f), hw2[j], o);
    }

    float x = o - 5.0f;
    out[gid] = 1.0f / (1.0f + expf(-x));
}

// ---------------- Fallback: fused kernel (if ws too small) ----------------
__global__ __launch_bounds__(256, 2) void rif_fused(
    const float* __restrict__ positions,
    const float* __restrict__ c2ws,
    const float* __restrict__ aabb,
    const float* __restrict__ table,
    const float* __restrict__ w1, const float* __restrict__ b1,
    const float* __restrict__ w2, const float* __restrict__ b2,
    const float* __restrict__ hw1, const float* __restrict__ hb1,
    const float* __restrict__ hw2, const float* __restrict__ hb2,
    float* __restrict__ out, int total, int S)
{
    int gid = blockIdx.x * 256 + threadIdx.x;
    if (gid >= total) return;
    int r = gid / S;
    const float* p = positions + (size_t)gid * 3;
    const float* c = c2ws + (size_t)r * 12;
    float px = p[0], py = p[1], pz = p[2];
    float c00 = c[0], c01 = c[1], c02 = c[2],  t0 = c[3];
    float c10 = c[4], c11 = c[5], c12 = c[6],  t1 = c[7];
    float c20 = c[8], c21 = c[9], c22 = c[10], t2 = c[11];
    float m0 = __fadd_rn(__fadd_rn(__fmul_rn(c00, px), __fmul_rn(c10, py)), __fmul_rn(c20, pz));
    float m1 = __fadd_rn(__fadd_rn(__fmul_rn(c01, px), __fmul_rn(c11, py)), __fmul_rn(c21, pz));
    float m2 = __fadd_rn(__fadd_rn(__fmul_rn(c02, px), __fmul_rn(c12, py)), __fmul_rn(c22, pz));
    float n0 = __fadd_rn(__fadd_rn(__fmul_rn(c00, t0), __fmul_rn(c10, t1)), __fmul_rn(c20, t2));
    float n1 = __fadd_rn(__fadd_rn(__fmul_rn(c01, t0), __fmul_rn(c11, t1)), __fmul_rn(c21, t2));
    float n2 = __fadd_rn(__fadd_rn(__fmul_rn(c02, t0), __fmul_rn(c12, t1)), __fmul_rn(c22, t2));
    float x0 = __fsub_rn(m0, n0);
    float x1 = __fsub_rn(m1, n1);
    float x2 = __fsub_rn(m2, n2);
    float a0x = aabb[0], a0y = aabb[1], a0z = aabb[2];
    float a1x = aabb[3], a1y = aabb[4], a1z = aabb[5];
    float posx = __fdiv_rn(__fsub_rn(x0, a0x), __fsub_rn(a1x, a0x));
    float posy = __fdiv_rn(__fsub_rn(x1, a0y), __fsub_rn(a1y, a0y));
    float posz = __fdiv_rn(__fsub_rn(x2, a0z), __fsub_rn(a1z, a0z));
    bool sel = (posx > 0.f) & (posx < 1.f) & (posy > 0.f) & (posy < 1.f) & (posz > 0.f) & (posz < 1.f);
    if (!sel) { out[gid] = 0.f; return; }

    const float kScale[8] = {16.f, 28.f, 52.f, 95.f, 172.f, 312.f, 565.f, 1024.f};
    float enc[16];
    #pragma unroll
    for (int l = 0; l < NLEV; ++l) {
        float sc = kScale[l];
        float sx = posx * sc, sy = posy * sc, sz = posz * sc;
        float fx = floorf(sx), fy = floorf(sy), fz = floorf(sz);
        float wx = sx - fx, wy = sy - fy, wz = sz - fz;
        uint32_t ix = (uint32_t)(int)fx, iy = (uint32_t)(int)fy, iz = (uint32_t)(int)fz;
        uint32_t hy0 = iy * 2654435761u, hy1 = hy0 + 2654435761u;
        uint32_t hz0 = iz * 805459861u,  hz1 = hz0 + 805459861u;
        const float2* tab = (const float2*)table + (size_t)l * TSIZE;
        float f0 = 0.f, f1 = 0.f;
        #pragma unroll
        for (int cc = 0; cc < 8; ++cc) {
            uint32_t cx = (cc >> 2) & 1, cy = (cc >> 1) & 1, cz = cc & 1;
            uint32_t hh = ((ix + cx) ^ (cy ? hy1 : hy0) ^ (cz ? hz1 : hz0)) & TMASK;
            float wgt = (cx ? wx : 1.f - wx) * (cy ? wy : 1.f - wy) * (cz ? wz : 1.f - wz);
            float2 ftv = tab[hh];
            f0 = fmaf(ftv.x, wgt, f0);
            f1 = fmaf(ftv.y, wgt, f1);
        }
        enc[2 * l] = f0;
        enc[2 * l + 1] = f1;
    }

    float h1[32];
    #pragma unroll
    for (int j = 0; j < 32; ++j) h1[j] = b1[j];
    #pragma unroll
    for (int i = 0; i < 16; ++i) {
        float e = enc[i];
        #pragma unroll
        for (int j = 0; j < 32; ++j) h1[j] = fmaf(e, w1[i * 32 + j], h1[j]);
    }
    #pragma unroll
    for (int j = 0; j < 32; ++j) h1[j] = fmaxf(h1[j], 0.f);

    float h2[16];
    #pragma unroll
    for (int j = 0; j < 16; ++j) h2[j] = b2[j];
    #pragma unroll
    for (int i = 0; i < 32; ++i) {
        float e = h1[i];
        #pragma unroll
        for (int j = 0; j < 16; ++j) h2[j] = fmaf(e, w2[i * 16 + j], h2[j]);
    }

    float o = hb2[0];
    #pragma unroll
    for (int j = 0; j < 64; ++j) {
        float acc = hb1[j];
        #pragma unroll
        for (int i = 0; i < 16; ++i) acc = fmaf(h2[i], hw1[i * 64 + j], acc);
        o = fmaf(fmaxf(acc, 0.f), hw2[j], o);
    }

    float x = o - 5.0f;
    out[gid] = 1.0f / (1.0f + expf(-x));
}

extern "C" void kernel_launch(void* const* d_in, const int* in_sizes, int n_in,
                              void* d_out, int out_size, void* d_ws, size_t ws_size,
                              hipStream_t stream) {
    const float* positions = (const float*)d_in[0];
    const float* c2ws      = (const float*)d_in[1];
    const float* aabb      = (const float*)d_in[2];
    const float* table     = (const float*)d_in[3];
    const float* w1  = (const float*)d_in[4];
    const float* b1  = (const float*)d_in[5];
    const float* w2  = (const float*)d_in[6];
    const float* b2  = (const float*)d_in[7];
    const float* hw1 = (const float*)d_in[8];
    const float* hb1 = (const float*)d_in[9];
    const float* hw2 = (const float*)d_in[10];
    const float* hb2 = (const float*)d_in[11];

    int R = in_sizes[1] / 12;
    int total = in_sizes[0] / 3;
    int S = total / R;

    size_t enc_bytes  = (size_t)total * 16 * sizeof(float);
    size_t pos_bytes  = (size_t)total * sizeof(float4);
    size_t needed = enc_bytes + pos_bytes;
    if (ws_size >= needed) {
        float*  encbuf = (float*)d_ws;
        float4* pos4   = (float4*)((char*)d_ws + enc_bytes);

        int blocks0 = (total + 255) / 256;
        hipLaunchKernelGGL(rif_xform, dim3(blocks0), dim3(256), 0, stream,
                           positions, c2ws, aabb, (float*)d_out, pos4, total, S);

        int nchunks = (total + 127) / 128;
        hipLaunchKernelGGL(rif_enc, dim3(nchunks * 4), dim3(256), 0, stream,
                           pos4, table, encbuf, total);

        hipLaunchKernelGGL(rif_mlp, dim3(blocks0), dim3(256), 0, stream,
                           pos4, w1, b1, w2, b2, hw1, hb1, hw2, hb2,
                           (float*)d_out, encbuf, total);
    } else {
        int blocks = (total + 255) / 256;
        hipLaunchKernelGGL(rif_fused, dim3(blocks), dim3(256), 0, stream,
                           positions, c2ws, aabb, table,
                           w1, b1, w2, b2, hw1, hb1, hw2, hb2,
                           (float*)d_out, total, S);
    }
}

// Round 9
// 73.954 us; speedup vs baseline: 1.2765x; 1.0594x over previous
//
#include <hip/hip_runtime.h>
#include <math.h>
#include <stdint.h>

#define NLEV 8
#define TSIZE 131072
#define TMASK (TSIZE - 1)

typedef float nfloat2 __attribute__((ext_vector_type(2)));

// ---------------- K0: transform once per sample ----------------
__global__ __launch_bounds__(256) void rif_xform(
    const float* __restrict__ positions,
    const float* __restrict__ c2ws,
    const float* __restrict__ aabb,
    float* __restrict__ out,
    float4* __restrict__ pos4,
    int total, int S)
{
    int gid = blockIdx.x * 256 + threadIdx.x;
    if (gid >= total) return;
    int r = gid / S;
    const float* p = positions + (size_t)gid * 3;
    const float* c = c2ws + (size_t)r * 12;
    float px = p[0], py = p[1], pz = p[2];
    float c00 = c[0], c01 = c[1], c02 = c[2],  t0 = c[3];
    float c10 = c[4], c11 = c[5], c12 = c[6],  t1 = c[7];
    float c20 = c[8], c21 = c[9], c22 = c[10], t2 = c[11];

    // reference op order, no FMA contraction (selector boundary must match)
    float m0 = __fadd_rn(__fadd_rn(__fmul_rn(c00, px), __fmul_rn(c10, py)), __fmul_rn(c20, pz));
    float m1 = __fadd_rn(__fadd_rn(__fmul_rn(c01, px), __fmul_rn(c11, py)), __fmul_rn(c21, pz));
    float m2 = __fadd_rn(__fadd_rn(__fmul_rn(c02, px), __fmul_rn(c12, py)), __fmul_rn(c22, pz));
    float n0 = __fadd_rn(__fadd_rn(__fmul_rn(c00, t0), __fmul_rn(c10, t1)), __fmul_rn(c20, t2));
    float n1 = __fadd_rn(__fadd_rn(__fmul_rn(c01, t0), __fmul_rn(c11, t1)), __fmul_rn(c21, t2));
    float n2 = __fadd_rn(__fadd_rn(__fmul_rn(c02, t0), __fmul_rn(c12, t1)), __fmul_rn(c22, t2));
    float x0 = __fsub_rn(m0, n0);
    float x1 = __fsub_rn(m1, n1);
    float x2 = __fsub_rn(m2, n2);

    float a0x = aabb[0], a0y = aabb[1], a0z = aabb[2];
    float a1x = aabb[3], a1y = aabb[4], a1z = aabb[5];
    float posx = __fdiv_rn(__fsub_rn(x0, a0x), __fsub_rn(a1x, a0x));
    float posy = __fdiv_rn(__fsub_rn(x1, a0y), __fsub_rn(a1y, a0y));
    float posz = __fdiv_rn(__fsub_rn(x2, a0z), __fsub_rn(a1z, a0z));
    bool sel = (posx > 0.f) & (posx < 1.f) & (posy > 0.f) & (posy < 1.f) & (posz > 0.f) & (posz < 1.f);

    if (!sel) out[gid] = 0.f;
    pos4[gid] = make_float4(posx, posy, posz, sel ? 1.f : 0.f);
}

// ---------------- K1: level-major hash encode, SoA float2 planes ----------------
// block = 256 threads = 128 samples x 2 paired levels (g, 7-g), g = blockIdx%4.
// Blocks round-robin XCDs -> each XCD touches only 2 subtables (2 MB) -> L2-resident.
// enc layout: 8 planes of float2, plane l at encf2 + l*total, index gid.
__global__ __launch_bounds__(256) void rif_enc(
    const float4* __restrict__ pos4,
    const float* __restrict__ table,
    nfloat2* __restrict__ encf2,
    int total)
{
    int g     = blockIdx.x & 3;
    int chunk = blockIdx.x >> 2;
    int half  = threadIdx.x >> 7;        // 0: level g, 1: level 7-g
    int sl    = threadIdx.x & 127;
    int gid   = chunk * 128 + sl;
    if (gid >= total) return;
    int l = half ? (7 - g) : g;

    float4 pp = pos4[gid];
    if (pp.w == 0.f) return;

    float sc = (l == 0) ? 16.f : (l == 1) ? 28.f : (l == 2) ? 52.f : (l == 3) ? 95.f
             : (l == 4) ? 172.f : (l == 5) ? 312.f : (l == 6) ? 565.f : 1024.f;

    float sx = pp.x * sc, sy = pp.y * sc, sz = pp.z * sc;
    float fx = floorf(sx), fy = floorf(sy), fz = floorf(sz);
    float wx = sx - fx, wy = sy - fy, wz = sz - fz;
    uint32_t ix = (uint32_t)(int)fx, iy = (uint32_t)(int)fy, iz = (uint32_t)(int)fz;
    uint32_t hy0 = iy * 2654435761u, hy1 = hy0 + 2654435761u;
    uint32_t hz0 = iz * 805459861u,  hz1 = hz0 + 805459861u;
    const float2* tab = (const float2*)table + (size_t)l * TSIZE;

    float2 ft[8];
    #pragma unroll
    for (int cc = 0; cc < 8; ++cc) {
        uint32_t cx = (cc >> 2) & 1, cy = (cc >> 1) & 1, cz = cc & 1;
        uint32_t hh = ((ix + cx) ^ (cy ? hy1 : hy0) ^ (cz ? hz1 : hz0)) & TMASK;
        ft[cc] = tab[hh];
    }
    __builtin_amdgcn_sched_barrier(0);

    float ux = 1.f - wx, uy = 1.f - wy, uz = 1.f - wz;
    float q00 = uy * uz, q01 = uy * wz, q10 = wy * uz, q11 = wy * wz;
    float f0, f1;
    f0 = ft[0].x * (ux * q00); f1 = ft[0].y * (ux * q00);
    f0 = fmaf(ft[1].x, ux * q01, f0); f1 = fmaf(ft[1].y, ux * q01, f1);
    f0 = fmaf(ft[2].x, ux * q10, f0); f1 = fmaf(ft[2].y, ux * q10, f1);
    f0 = fmaf(ft[3].x, ux * q11, f0); f1 = fmaf(ft[3].y, ux * q11, f1);
    f0 = fmaf(ft[4].x, wx * q00, f0); f1 = fmaf(ft[4].y, wx * q00, f1);
    f0 = fmaf(ft[5].x, wx * q01, f0); f1 = fmaf(ft[5].y, wx * q01, f1);
    f0 = fmaf(ft[6].x, wx * q10, f0); f1 = fmaf(ft[6].y, wx * q10, f1);
    f0 = fmaf(ft[7].x, wx * q11, f0); f1 = fmaf(ft[7].y, wx * q11, f1);

    // plane store: lanes sl consecutive -> 512B contiguous per wave, lines owned by this block
    nfloat2 v; v.x = f0; v.y = f1;
    __builtin_nontemporal_store(v, encf2 + (size_t)l * total + gid);
}

// ---------------- K2: MLP (no compaction; coalesced plane reads) ----------------
__global__ __launch_bounds__(256) void rif_mlp(
    const float4* __restrict__ pos4,
    const float* __restrict__ w1, const float* __restrict__ b1,
    const float* __restrict__ w2, const float* __restrict__ b2,
    const float* __restrict__ hw1, const float* __restrict__ hb1,
    const float* __restrict__ hw2, const float* __restrict__ hb2,
    float* __restrict__ out,
    const nfloat2* __restrict__ encf2,
    int total)
{
    int gid = blockIdx.x * 256 + threadIdx.x;
    if (gid >= total) return;
    if (pos4[gid].w == 0.f) return;   // out already zeroed by K0

    float enc[16];
    #pragma unroll
    for (int l = 0; l < 8; ++l) {
        nfloat2 v = __builtin_nontemporal_load(encf2 + (size_t)l * total + gid);
        enc[2 * l] = v.x; enc[2 * l + 1] = v.y;
    }

    float h1[32];
    #pragma unroll
    for (int j = 0; j < 32; ++j) h1[j] = b1[j];
    #pragma unroll
    for (int i = 0; i < 16; ++i) {
        float e = enc[i];
        #pragma unroll
        for (int j = 0; j < 32; ++j) h1[j] = fmaf(e, w1[i * 32 + j], h1[j]);
    }
    #pragma unroll
    for (int j = 0; j < 32; ++j) h1[j] = fmaxf(h1[j], 0.f);

    float h2[16];
    #pragma unroll
    for (int j = 0; j < 16; ++j) h2[j] = b2[j];
    #pragma unroll
    for (int i = 0; i < 32; ++i) {
        float e = h1[i];
        #pragma unroll
        for (int j = 0; j < 16; ++j) h2[j] = fmaf(e, w2[i * 16 + j], h2[j]);
    }

    float o = hb2[0];
    #pragma unroll
    for (int j = 0; j < 64; ++j) {
        float acc = hb1[j];
        #pragma unroll
        for (int i = 0; i < 16; ++i) acc = fmaf(h2[i], hw1[i * 64 + j], acc);
        o = fmaf(fmaxf(acc, 0.f), hw2[j], o);
    }

    float x = o - 5.0f;
    out[gid] = 1.0f / (1.0f + expf(-x));
}

// ---------------- Fallback: fused kernel (if ws too small) ----------------
__global__ __launch_bounds__(256, 2) void rif_fused(
    const float* __restrict__ positions,
    const float* __restrict__ c2ws,
    const float* __restrict__ aabb,
    const float* __restrict__ table,
    const float* __restrict__ w1, const float* __restrict__ b1,
    const float* __restrict__ w2, const float* __restrict__ b2,
    const float* __restrict__ hw1, const float* __restrict__ hb1,
    const float* __restrict__ hw2, const float* __restrict__ hb2,
    float* __restrict__ out, int total, int S)
{
    int gid = blockIdx.x * 256 + threadIdx.x;
    if (gid >= total) return;
    int r = gid / S;
    const float* p = positions + (size_t)gid * 3;
    const float* c = c2ws + (size_t)r * 12;
    float px = p[0], py = p[1], pz = p[2];
    float c00 = c[0], c01 = c[1], c02 = c[2],  t0 = c[3];
    float c10 = c[4], c11 = c[5], c12 = c[6],  t1 = c[7];
    float c20 = c[8], c21 = c[9], c22 = c[10], t2 = c[11];
    float m0 = __fadd_rn(__fadd_rn(__fmul_rn(c00, px), __fmul_rn(c10, py)), __fmul_rn(c20, pz));
    float m1 = __fadd_rn(__fadd_rn(__fmul_rn(c01, px), __fmul_rn(c11, py)), __fmul_rn(c21, pz));
    float m2 = __fadd_rn(__fadd_rn(__fmul_rn(c02, px), __fmul_rn(c12, py)), __fmul_rn(c22, pz));
    float n0 = __fadd_rn(__fadd_rn(__fmul_rn(c00, t0), __fmul_rn(c10, t1)), __fmul_rn(c20, t2));
    float n1 = __fadd_rn(__fadd_rn(__fmul_rn(c01, t0), __fmul_rn(c11, t1)), __fmul_rn(c21, t2));
    float n2 = __fadd_rn(__fadd_rn(__fmul_rn(c02, t0), __fmul_rn(c12, t1)), __fmul_rn(c22, t2));
    float x0 = __fsub_rn(m0, n0);
    float x1 = __fsub_rn(m1, n1);
    float x2 = __fsub_rn(m2, n2);
    float a0x = aabb[0], a0y = aabb[1], a0z = aabb[2];
    float a1x = aabb[3], a1y = aabb[4], a1z = aabb[5];
    float posx = __fdiv_rn(__fsub_rn(x0, a0x), __fsub_rn(a1x, a0x));
    float posy = __fdiv_rn(__fsub_rn(x1, a0y), __fsub_rn(a1y, a0y));
    float posz = __fdiv_rn(__fsub_rn(x2, a0z), __fsub_rn(a1z, a0z));
    bool sel = (posx > 0.f) & (posx < 1.f) & (posy > 0.f) & (posy < 1.f) & (posz > 0.f) & (posz < 1.f);
    if (!sel) { out[gid] = 0.f; return; }

    const float kScale[8] = {16.f, 28.f, 52.f, 95.f, 172.f, 312.f, 565.f, 1024.f};
    float enc[16];
    #pragma unroll
    for (int l = 0; l < NLEV; ++l) {
        float sc = kScale[l];
        float sx = posx * sc, sy = posy * sc, sz = posz * sc;
        float fx = floorf(sx), fy = floorf(sy), fz = floorf(sz);
        float wx = sx - fx, wy = sy - fy, wz = sz - fz;
        uint32_t ix = (uint32_t)(int)fx, iy = (uint32_t)(int)fy, iz = (uint32_t)(int)fz;
        uint32_t hy0 = iy * 2654435761u, hy1 = hy0 + 2654435761u;
        uint32_t hz0 = iz * 805459861u,  hz1 = hz0 + 805459861u;
        const float2* tab = (const float2*)table + (size_t)l * TSIZE;
        float f0 = 0.f, f1 = 0.f;
        #pragma unroll
        for (int cc = 0; cc < 8; ++cc) {
            uint32_t cx = (cc >> 2) & 1, cy = (cc >> 1) & 1, cz = cc & 1;
            uint32_t hh = ((ix + cx) ^ (cy ? hy1 : hy0) ^ (cz ? hz1 : hz0)) & TMASK;
            float wgt = (cx ? wx : 1.f - wx) * (cy ? wy : 1.f - wy) * (cz ? wz : 1.f - wz);
            float2 ftv = tab[hh];
            f0 = fmaf(ftv.x, wgt, f0);
            f1 = fmaf(ftv.y, wgt, f1);
        }
        enc[2 * l] = f0;
        enc[2 * l + 1] = f1;
    }

    float h1[32];
    #pragma unroll
    for (int j = 0; j < 32; ++j) h1[j] = b1[j];
    #pragma unroll
    for (int i = 0; i < 16; ++i) {
        float e = enc[i];
        #pragma unroll
        for (int j = 0; j < 32; ++j) h1[j] = fmaf(e, w1[i * 32 + j], h1[j]);
    }
    #pragma unroll
    for (int j = 0; j < 32; ++j) h1[j] = fmaxf(h1[j], 0.f);

    float h2[16];
    #pragma unroll
    for (int j = 0; j < 16; ++j) h2[j] = b2[j];
    #pragma unroll
    for (int i = 0; i < 32; ++i) {
        float e = h1[i];
        #pragma unroll
        for (int j = 0; j < 16; ++j) h2[j] = fmaf(e, w2[i * 16 + j], h2[j]);
    }

    float o = hb2[0];
    #pragma unroll
    for (int j = 0; j < 64; ++j) {
        float acc = hb1[j];
        #pragma unroll
        for (int i = 0; i < 16; ++i) acc = fmaf(h2[i], hw1[i * 64 + j], acc);
        o = fmaf(fmaxf(acc, 0.f), hw2[j], o);
    }

    float x = o - 5.0f;
    out[gid] = 1.0f / (1.0f + expf(-x));
}

extern "C" void kernel_launch(void* const* d_in, const int* in_sizes, int n_in,
                              void* d_out, int out_size, void* d_ws, size_t ws_size,
                              hipStream_t stream) {
    const float* positions = (const float*)d_in[0];
    const float* c2ws      = (const float*)d_in[1];
    const float* aabb      = (const float*)d_in[2];
    const float* table     = (const float*)d_in[3];
    const float* w1  = (const float*)d_in[4];
    const float* b1  = (const float*)d_in[5];
    const float* w2  = (const float*)d_in[6];
    const float* b2  = (const float*)d_in[7];
    const float* hw1 = (const float*)d_in[8];
    const float* hb1 = (const float*)d_in[9];
    const float* hw2 = (const float*)d_in[10];
    const float* hb2 = (const float*)d_in[11];

    int R = in_sizes[1] / 12;
    int total = in_sizes[0] / 3;
    int S = total / R;

    size_t enc_bytes  = (size_t)total * 8 * sizeof(nfloat2);
    size_t pos_bytes  = (size_t)total * sizeof(float4);
    size_t needed = enc_bytes + pos_bytes;
    if (ws_size >= needed) {
        nfloat2* encf2 = (nfloat2*)d_ws;
        float4*  pos4  = (float4*)((char*)d_ws + enc_bytes);

        int blocks0 = (total + 255) / 256;
        hipLaunchKernelGGL(rif_xform, dim3(blocks0), dim3(256), 0, stream,
                           positions, c2ws, aabb, (float*)d_out, pos4, total, S);

        int nchunks = (total + 127) / 128;
        hipLaunchKernelGGL(rif_enc, dim3(nchunks * 4), dim3(256), 0, stream,
                           pos4, table, encf2, total);

        hipLaunchKernelGGL(rif_mlp, dim3(blocks0), dim3(256), 0, stream,
                           pos4, w1, b1, w2, b2, hw1, hb1, hw2, hb2,
                           (float*)d_out, encf2, total);
    } else {
        int blocks = (total + 255) / 256;
        hipLaunchKernelGGL(rif_fused, dim3(blocks), dim3(256), 0, stream,
                           positions, c2ws, aabb, table,
                           w1, b1, w2, b2, hw1, hb1, hw2, hb2,
                           (float*)d_out, total, S);
    }
}